// Round 13
// baseline (18.239 us; speedup 1.0000x reference)
//
#include <hip/hip_runtime.h>
#include <hip/hip_bf16.h>

#define BB 4096
#define CC 256
#define DD 512
#define SS 8

#define BM 64
#define BN 64
#define BK 64

typedef __attribute__((ext_vector_type(4))) float f32x4;
typedef __attribute__((ext_vector_type(8))) short s16x8;

// float -> bf16 bits, RNE via HW cvt
static __device__ inline short f2bf(float f) {
    __hip_bfloat16 h = __float2bfloat16(f);
    return *reinterpret_cast<short*>(&h);
}

// Single kernel, grid = 512 flat: s = bid&7 (XCD affinity), rt0 = (bid>>3)&7, ct = bid>>6
// Each block loops rt = rt0, rt0+8, ... while rt*64 < n_s  (typically exactly 1 iter).
// R13 = R12 + all-useful grid (rt-loop). GEMM body identical to R12.
__global__ __launch_bounds__(256) void fused_kernel(
    const float* __restrict__ x, const int* __restrict__ subj,
    const float* __restrict__ w, const float* __restrict__ bias,
    float* __restrict__ out)
{
    const int s   = blockIdx.x & 7;
    const int rt0 = (blockIdx.x >> 3) & 7;
    const int ct  = blockIdx.x >> 6;
    const int tid = threadIdx.x;
    const int lane = tid & 63, wv = tid >> 6;
    const unsigned long long lt = (1ull << lane) - 1ull;

    __shared__ __align__(16) short As[2][BM * BK];       // 2 x 8KB, swizzled
    __shared__ __align__(16) short Bs[2][BK / 8][BN][8]; // 2 x 8KB, k-blocked
    __shared__ int wcnt[16][4];                          // own-subject counts
    __shared__ int pre[16][4];                           // exclusive prefix
    __shared__ int rows_l[BM];
    __shared__ int ns_sh;

    // ---- T14: issue ks=0 W loads NOW (need only s, ct); pin before binning
    const float* wb = w + (size_t)s * CC * DD + ct * BN + lane;  // column = lane
    float wf[2][8];
    auto BLOAD = [&](int ks) {
#pragma unroll
        for (int i = 0; i < 2; ++i) {
            int kb = wv + i * 4;
#pragma unroll
            for (int e = 0; e < 8; ++e)
                wf[i][e] = wb[(size_t)(ks * BK + kb * 8 + e) * DD];
        }
    };
    BLOAD(0);
    asm volatile("" ::: "memory");   // don't sink the W loads past binning

    // ---- wave/frag geometry + bias hoist (latency hides under binning)
    const int wm = wv & 1, wn = wv >> 1;
    const int lr = lane & 15, lg = lane >> 4;
    float bv[2];
#pragma unroll
    for (int nf = 0; nf < 2; ++nf)
        bv[nf] = bias[s * DD + ct * BN + wn * 32 + nf * 16 + lr];

    // ---- binning pass 1: own-subject counts per (chunk, wave)
    int sl[16];
#pragma unroll
    for (int i = 0; i < 16; ++i) sl[i] = subj[tid + i * 256];
#pragma unroll
    for (int i = 0; i < 16; ++i) {
        unsigned long long m = __ballot(sl[i] == s);
        if (lane == 0) wcnt[i][wv] = __popcll(m);
    }
    __syncthreads();

    // ---- 64-entry exclusive scan (chunk-major, wave-minor) in wave 0
    if (tid < 64) {
        int c = wcnt[tid >> 2][tid & 3];
        int inc = c;
#pragma unroll
        for (int d2 = 1; d2 < 64; d2 <<= 1) {
            int o = __shfl_up(inc, d2, 64);
            if (lane >= d2) inc += o;
        }
        pre[tid >> 2][tid & 3] = inc - c;
        if (tid == 63) ns_sh = inc;
    }
    __syncthreads();

    const int n_s = ns_sh;
    if (rt0 * BM >= n_s) return;                         // uniform early exit

    const int ar = tid >> 2;                   // A row (4 threads/row)

    for (int rt = rt0; rt * BM < n_s; rt += 8) {
        if (rt != rt0) {
            __syncthreads();                   // prev epilogue done with rows_l
            BLOAD(0);                          // W regs for this iter (L2-hot)
        }
        int m_valid = n_s - rt * BM; if (m_valid > BM) m_valid = BM;

        if (tid < BM) rows_l[tid] = -1;
        __syncthreads();

        // ---- binning pass 2: place this tile's rows
#pragma unroll
        for (int i = 0; i < 16; ++i) {
            unsigned long long m = __ballot(sl[i] == s);
            if (sl[i] == s) {
                int rank = pre[i][wv] + __popcll(m & lt);
                int p = rank - rt * BM;
                if (p >= 0 && p < BM) rows_l[p] = tid + i * 256;
            }
        }
        __syncthreads();

        // ---- GEMM (R12 dbuf body)
        f32x4 acc[2][2];
#pragma unroll
        for (int mf = 0; mf < 2; ++mf)
#pragma unroll
            for (int nf = 0; nf < 2; ++nf)
                acc[mf][nf] = (f32x4)0.0f;

        const int grow = rows_l[ar];
        const float* xp = x + (size_t)(grow < 0 ? 0 : grow) * CC + (tid & 3) * 16;

        f32x4 xa[4];                           // next A chunk (16 floats)

        auto ALOAD = [&](int ks) {
            if (grow >= 0) {
#pragma unroll
                for (int i = 0; i < 4; ++i)
                    xa[i] = *reinterpret_cast<const f32x4*>(xp + ks * BK + i * 4);
            } else {
#pragma unroll
                for (int i = 0; i < 4; ++i) xa[i] = (f32x4)0.0f;
            }
        };
        auto STORE = [&](int pb) {
#pragma unroll
            for (int i = 0; i < 2; ++i) {
                s16x8 p;
                p[0] = f2bf(xa[2 * i][0]); p[1] = f2bf(xa[2 * i][1]);
                p[2] = f2bf(xa[2 * i][2]); p[3] = f2bf(xa[2 * i][3]);
                p[4] = f2bf(xa[2 * i + 1][0]); p[5] = f2bf(xa[2 * i + 1][1]);
                p[6] = f2bf(xa[2 * i + 1][2]); p[7] = f2bf(xa[2 * i + 1][3]);
                int c = (tid & 3) * 2 + i;
                *reinterpret_cast<s16x8*>(reinterpret_cast<char*>(As[pb])
                    + ar * 128 + ((c * 16) ^ ((ar & 7) << 4))) = p;
            }
#pragma unroll
            for (int i = 0; i < 2; ++i) {
                s16x8 p;
#pragma unroll
                for (int e = 0; e < 8; ++e) p[e] = f2bf(wf[i][e]);
                *reinterpret_cast<s16x8*>(&Bs[pb][wv + i * 4][lane][0]) = p;
            }
        };
        auto COMPUTE = [&](int pb) {
            s16x8 af[2][2], bfr[2][2];
#pragma unroll
            for (int mf = 0; mf < 2; ++mf) {
                int row = wm * 32 + mf * 16 + lr;
#pragma unroll
                for (int kh = 0; kh < 2; ++kh) {
                    int kf2 = (kh * 32 + lg * 8) * 2;
                    af[mf][kh] = *reinterpret_cast<s16x8*>(reinterpret_cast<char*>(As[pb])
                        + row * 128 + (kf2 ^ ((row & 7) << 4)));
                }
            }
#pragma unroll
            for (int nf = 0; nf < 2; ++nf) {
                int n = wn * 32 + nf * 16 + lr;
#pragma unroll
                for (int kh = 0; kh < 2; ++kh)
                    bfr[nf][kh] = *reinterpret_cast<s16x8*>(&Bs[pb][kh * 4 + lg][n][0]);
            }
#pragma unroll
            for (int mf = 0; mf < 2; ++mf)
#pragma unroll
                for (int nf = 0; nf < 2; ++nf)
#pragma unroll
                    for (int kh = 0; kh < 2; ++kh)
                        acc[mf][nf] = __builtin_amdgcn_mfma_f32_16x16x32_bf16(
                            af[mf][kh], bfr[nf][kh], acc[mf][nf], 0, 0, 0);
        };

        ALOAD(0);
        STORE(0);
        __syncthreads();
#pragma unroll
        for (int ks = 0; ks < CC / BK - 1; ++ks) {
            BLOAD(ks + 1);          // W regs for next step
            ALOAD(ks + 1);          // A regs for next step (hide under MFMA)
            COMPUTE(ks & 1);
            STORE((ks + 1) & 1);    // opposite buffer: no pre-write barrier needed
            __syncthreads();
        }
        COMPUTE((CC / BK - 1) & 1);

        // ---- epilogue: + bias, scatter rows back
#pragma unroll
        for (int nf = 0; nf < 2; ++nf) {
            int col = ct * BN + wn * 32 + nf * 16 + lr;
#pragma unroll
            for (int mf = 0; mf < 2; ++mf) {
                int rl0 = wm * 32 + mf * 16 + lg * 4;
#pragma unroll
                for (int r = 0; r < 4; ++r) {
                    int rl = rl0 + r;
                    if (rl < m_valid) {
                        int g = rows_l[rl];
                        out[(size_t)g * DD + col] = acc[mf][nf][r] + bv[nf];
                    }
                }
            }
        }
    }
}

extern "C" void kernel_launch(void* const* d_in, const int* in_sizes, int n_in,
                              void* d_out, int out_size, void* d_ws, size_t ws_size,
                              hipStream_t stream) {
    const float* x        = (const float*)d_in[0];
    const int*   subjects = (const int*)d_in[1];
    const float* weights  = (const float*)d_in[2];
    const float* bias     = (const float*)d_in[3];
    float* out = (float*)d_out;

    fused_kernel<<<512, 256, 0, stream>>>(x, subjects, weights, bias, out);
}

// Round 14
// 16.610 us; speedup vs baseline: 1.0981x; 1.0981x over previous
//
#include <hip/hip_runtime.h>
#include <hip/hip_bf16.h>

#define BB 4096
#define CC 256
#define DD 512
#define SS 8

#define BM 64
#define BN 64
#define BK 64

typedef __attribute__((ext_vector_type(4))) float f32x4;
typedef __attribute__((ext_vector_type(8))) short s16x8;

// float -> bf16 bits, RNE via HW cvt
static __device__ inline short f2bf(float f) {
    __hip_bfloat16 h = __float2bfloat16(f);
    return *reinterpret_cast<short*>(&h);
}

// Single kernel, grid = 1024 flat: s = bid&7 (XCD affinity), rt=(bid>>3)&15, ct=bid>>7
// R14 = R12 verbatim (best measured: 16.77us).
//   - one node (no prep kernel, no ws, no graph dependency edge)
//   - own-subject ballot binning, uniform early exit (~half the blocks)
//   - W ks=0 register loads issued at kernel ENTRY (cold-HBM latency under binning)
//   - bias hoisted; dbuf LDS; 1 barrier/K-step; inline HW cvt fp32->bf16
__global__ __launch_bounds__(256) void fused_kernel(
    const float* __restrict__ x, const int* __restrict__ subj,
    const float* __restrict__ w, const float* __restrict__ bias,
    float* __restrict__ out)
{
    const int s  = blockIdx.x & 7;
    const int rt = (blockIdx.x >> 3) & 15;
    const int ct = blockIdx.x >> 7;
    const int tid = threadIdx.x;
    const int lane = tid & 63, wv = tid >> 6;
    const unsigned long long lt = (1ull << lane) - 1ull;

    __shared__ __align__(16) short As[2][BM * BK];       // 2 x 8KB, swizzled
    __shared__ __align__(16) short Bs[2][BK / 8][BN][8]; // 2 x 8KB, k-blocked
    __shared__ int wcnt[16][4];                          // own-subject counts
    __shared__ int pre[16][4];                           // exclusive prefix
    __shared__ int rows_l[BM];
    __shared__ int ns_sh;

    // ---- T14: issue ks=0 W loads NOW (need only s, ct); pin before binning
    const float* wb = w + (size_t)s * CC * DD + ct * BN + lane;  // column = lane
    float wf[2][8];
    auto BLOAD = [&](int ks) {
#pragma unroll
        for (int i = 0; i < 2; ++i) {
            int kb = wv + i * 4;
#pragma unroll
            for (int e = 0; e < 8; ++e)
                wf[i][e] = wb[(size_t)(ks * BK + kb * 8 + e) * DD];
        }
    };
    BLOAD(0);
    asm volatile("" ::: "memory");   // don't sink the W loads past binning

    if (tid < BM) rows_l[tid] = -1;

    // ---- binning pass 1: own-subject counts per (chunk, wave)
    int sl[16];
#pragma unroll
    for (int i = 0; i < 16; ++i) sl[i] = subj[tid + i * 256];
#pragma unroll
    for (int i = 0; i < 16; ++i) {
        unsigned long long m = __ballot(sl[i] == s);
        if (lane == 0) wcnt[i][wv] = __popcll(m);
    }
    __syncthreads();

    // ---- 64-entry exclusive scan (chunk-major, wave-minor) in wave 0
    if (tid < 64) {
        int c = wcnt[tid >> 2][tid & 3];
        int inc = c;
#pragma unroll
        for (int d2 = 1; d2 < 64; d2 <<= 1) {
            int o = __shfl_up(inc, d2, 64);
            if (lane >= d2) inc += o;
        }
        pre[tid >> 2][tid & 3] = inc - c;
        if (tid == 63) ns_sh = inc;
    }
    __syncthreads();

    const int n_s = ns_sh;
    if (rt * BM >= n_s) return;                          // uniform early exit
    int m_valid = n_s - rt * BM; if (m_valid > BM) m_valid = BM;

    // ---- wave/frag geometry + bias hoist (latency hides under pass 2)
    const int wm = wv & 1, wn = wv >> 1;
    const int lr = lane & 15, lg = lane >> 4;
    float bv[2];
#pragma unroll
    for (int nf = 0; nf < 2; ++nf)
        bv[nf] = bias[s * DD + ct * BN + wn * 32 + nf * 16 + lr];

    // ---- binning pass 2: place this tile's rows
#pragma unroll
    for (int i = 0; i < 16; ++i) {
        unsigned long long m = __ballot(sl[i] == s);
        if (sl[i] == s) {
            int rank = pre[i][wv] + __popcll(m & lt);
            int p = rank - rt * BM;
            if (p >= 0 && p < BM) rows_l[p] = tid + i * 256;
        }
    }
    __syncthreads();

    // ---- GEMM (dbuf body)
    f32x4 acc[2][2];
#pragma unroll
    for (int mf = 0; mf < 2; ++mf)
#pragma unroll
        for (int nf = 0; nf < 2; ++nf)
            acc[mf][nf] = (f32x4)0.0f;

    const int ar = tid >> 2;                   // A row (4 threads/row)
    const int grow = rows_l[ar];
    const float* xp = x + (size_t)(grow < 0 ? 0 : grow) * CC + (tid & 3) * 16;

    f32x4 xa[4];                               // next A chunk (16 floats)

    auto ALOAD = [&](int ks) {
        if (grow >= 0) {
#pragma unroll
            for (int i = 0; i < 4; ++i)
                xa[i] = *reinterpret_cast<const f32x4*>(xp + ks * BK + i * 4);
        } else {
#pragma unroll
            for (int i = 0; i < 4; ++i) xa[i] = (f32x4)0.0f;
        }
    };
    auto STORE = [&](int pb) {
#pragma unroll
        for (int i = 0; i < 2; ++i) {
            s16x8 p;
            p[0] = f2bf(xa[2 * i][0]); p[1] = f2bf(xa[2 * i][1]);
            p[2] = f2bf(xa[2 * i][2]); p[3] = f2bf(xa[2 * i][3]);
            p[4] = f2bf(xa[2 * i + 1][0]); p[5] = f2bf(xa[2 * i + 1][1]);
            p[6] = f2bf(xa[2 * i + 1][2]); p[7] = f2bf(xa[2 * i + 1][3]);
            int c = (tid & 3) * 2 + i;
            *reinterpret_cast<s16x8*>(reinterpret_cast<char*>(As[pb])
                + ar * 128 + ((c * 16) ^ ((ar & 7) << 4))) = p;
        }
#pragma unroll
        for (int i = 0; i < 2; ++i) {
            s16x8 p;
#pragma unroll
            for (int e = 0; e < 8; ++e) p[e] = f2bf(wf[i][e]);
            *reinterpret_cast<s16x8*>(&Bs[pb][wv + i * 4][lane][0]) = p;
        }
    };
    auto COMPUTE = [&](int pb) {
        s16x8 af[2][2], bfr[2][2];
#pragma unroll
        for (int mf = 0; mf < 2; ++mf) {
            int row = wm * 32 + mf * 16 + lr;
#pragma unroll
            for (int kh = 0; kh < 2; ++kh) {
                int kf2 = (kh * 32 + lg * 8) * 2;
                af[mf][kh] = *reinterpret_cast<s16x8*>(reinterpret_cast<char*>(As[pb])
                    + row * 128 + (kf2 ^ ((row & 7) << 4)));
            }
        }
#pragma unroll
        for (int nf = 0; nf < 2; ++nf) {
            int n = wn * 32 + nf * 16 + lr;
#pragma unroll
            for (int kh = 0; kh < 2; ++kh)
                bfr[nf][kh] = *reinterpret_cast<s16x8*>(&Bs[pb][kh * 4 + lg][n][0]);
        }
#pragma unroll
        for (int mf = 0; mf < 2; ++mf)
#pragma unroll
            for (int nf = 0; nf < 2; ++nf)
#pragma unroll
                for (int kh = 0; kh < 2; ++kh)
                    acc[mf][nf] = __builtin_amdgcn_mfma_f32_16x16x32_bf16(
                        af[mf][kh], bfr[nf][kh], acc[mf][nf], 0, 0, 0);
    };

    ALOAD(0);
    STORE(0);
    __syncthreads();
#pragma unroll
    for (int ks = 0; ks < CC / BK - 1; ++ks) {
        BLOAD(ks + 1);          // W regs for next step
        ALOAD(ks + 1);          // A regs for next step (hide under MFMA)
        COMPUTE(ks & 1);
        STORE((ks + 1) & 1);    // opposite buffer: no pre-write barrier needed
        __syncthreads();
    }
    COMPUTE((CC / BK - 1) & 1);

    // ---- epilogue: + bias, scatter rows back
#pragma unroll
    for (int nf = 0; nf < 2; ++nf) {
        int col = ct * BN + wn * 32 + nf * 16 + lr;
#pragma unroll
        for (int mf = 0; mf < 2; ++mf) {
            int rl0 = wm * 32 + mf * 16 + lg * 4;
#pragma unroll
            for (int r = 0; r < 4; ++r) {
                int rl = rl0 + r;
                if (rl < m_valid) {
                    int g = rows_l[rl];
                    out[(size_t)g * DD + col] = acc[mf][nf][r] + bv[nf];
                }
            }
        }
    }
}

extern "C" void kernel_launch(void* const* d_in, const int* in_sizes, int n_in,
                              void* d_out, int out_size, void* d_ws, size_t ws_size,
                              hipStream_t stream) {
    const float* x        = (const float*)d_in[0];
    const int*   subjects = (const int*)d_in[1];
    const float* weights  = (const float*)d_in[2];
    const float* bias     = (const float*)d_in[3];
    float* out = (float*)d_out;

    fused_kernel<<<1024, 256, 0, stream>>>(x, subjects, weights, bias, out);
}